// Round 8
// baseline (223.706 us; speedup 1.0000x reference)
//
#include <hip/hip_runtime.h>
#include <stdint.h>

#define M_DIM 8192
#define N_DIM 4096
#define K_DIM 4096
#define QMAXF 127.0f
#define QDIVF 127.5f

typedef int v4i __attribute__((ext_vector_type(4)));

// ---------------- address-space helpers for global_load_lds ----------------
typedef __attribute__((address_space(3))) void lds_void_t;
typedef __attribute__((address_space(1))) const void glb_void_t;

static __device__ __forceinline__ void load_lds16(const void* g, void* l) {
    __builtin_amdgcn_global_load_lds((glb_void_t*)g, (lds_void_t*)l, 16, 0, 0);
}

// ---- kernel 1: fused prep pass 1: [row absmax+quant lhs] ∥ [col absmax rhs] ----
__global__ __launch_bounds__(256) void prep1_kernel(
        const float* __restrict__ lhs, const float* __restrict__ rhs,
        float* __restrict__ sL, unsigned* __restrict__ bits,
        int8_t* __restrict__ ql) {
    const int t = threadIdx.x;
    if (blockIdx.x < M_DIM) {
        const int row = blockIdx.x;
        const float4* rp = (const float4*)(lhs + (size_t)row * K_DIM);
        float4 v[4];
        float m = 0.0f;
#pragma unroll
        for (int i = 0; i < 4; ++i) {
            v[i] = rp[t + i * 256];
            m = fmaxf(m, fmaxf(fmaxf(fabsf(v[i].x), fabsf(v[i].y)),
                               fmaxf(fabsf(v[i].z), fabsf(v[i].w))));
        }
#pragma unroll
        for (int off = 32; off; off >>= 1) m = fmaxf(m, __shfl_down(m, off, 64));
        __shared__ float wmax[4];
        if ((t & 63) == 0) wmax[t >> 6] = m;
        __syncthreads();
        const float mm = fmaxf(fmaxf(wmax[0], wmax[1]), fmaxf(wmax[2], wmax[3]));
        float s = mm / QDIVF;
        s = (s == 0.0f) ? 1.0f : s;
        if (t == 0) sL[row] = s;
        unsigned* qo = (unsigned*)ql + (size_t)row * 1024;
#pragma unroll
        for (int i = 0; i < 4; ++i) {
            int q0 = (int)fminf(fmaxf(rintf(v[i].x / s), -QMAXF), QMAXF);
            int q1 = (int)fminf(fmaxf(rintf(v[i].y / s), -QMAXF), QMAXF);
            int q2 = (int)fminf(fmaxf(rintf(v[i].z / s), -QMAXF), QMAXF);
            int q3 = (int)fminf(fmaxf(rintf(v[i].w / s), -QMAXF), QMAXF);
            qo[t + i * 256] = (q0 & 255) | ((q1 & 255) << 8) | ((q2 & 255) << 16)
                            | ((unsigned)(q3 & 255) << 24);
        }
    } else {
        const int cb = blockIdx.x - M_DIM;     // 0..1023
        const int col = (cb & 15) * 256 + t;
        const int r0 = (cb >> 4) * 64;
        float m = 0.0f;
#pragma unroll 4
        for (int r = 0; r < 64; ++r)
            m = fmaxf(m, fabsf(rhs[(size_t)(r0 + r) * N_DIM + col]));
        atomicMax(&bits[col], __float_as_uint(m));   // abs >= 0: bit order == float order
    }
}

// -- kernel 2: quantize + transpose rhs -> q_rT [N][K]; also materialize sR --
__global__ __launch_bounds__(256) void quant_rhs_t_kernel(
        const float* __restrict__ rhs, const unsigned* __restrict__ bits,
        float* __restrict__ sR, int8_t* __restrict__ qbT) {
    __shared__ __align__(16) int8_t lt[64][80];
    const int n0 = blockIdx.x * 64;
    const int k0 = blockIdx.y * 64;
    const int t = threadIdx.x;
    const int nloc = t & 63;
    const int kq = (t >> 6) * 16;
    float s = __uint_as_float(bits[n0 + nloc]) / QDIVF;
    s = (s == 0.0f) ? 1.0f : s;
    if (blockIdx.y == 0 && t < 64) {
        float ss = __uint_as_float(bits[n0 + t]) / QDIVF;
        sR[n0 + t] = (ss == 0.0f) ? 1.0f : ss;
    }
#pragma unroll
    for (int i = 0; i < 4; ++i) {
        unsigned pack = 0;
#pragma unroll
        for (int j = 0; j < 4; ++j) {
            int kk = kq + i * 4 + j;
            float x = rhs[(size_t)(k0 + kk) * N_DIM + n0 + nloc];
            int q = (int)fminf(fmaxf(rintf(x / s), -QMAXF), QMAXF);
            pack |= (unsigned)(q & 255) << (8 * j);
        }
        *(unsigned*)&lt[nloc][kq + i * 4] = pack;
    }
    __syncthreads();
    const int nn = t >> 2, ch = t & 3;
    v4i val = *(const v4i*)&lt[nn][ch * 16];
    *(v4i*)&qbT[(size_t)(n0 + nn) * K_DIM + k0 + ch * 16] = val;
}

// ===== kernel 3: int8 GEMM, 128x256 tile, BK=64, ring-3, 2 blocks/CU =====
// mfma_i32_16x16x64_i8 (conflict-free swizzle family, R5-validated).
// 72 KB LDS (3 x 24KB bufs) + VGPR <= 128 (launch_bounds 512,4) -> 2
// independent blocks per CU. No common barrier between blocks -> their
// LDS/lgkm phases and MFMA phases cross-fill (the R2..R7 serialization
// was barrier-lockstep of all resident waves).
// Schedule invariant (R5): at the barrier ending tile KT, tiles <= KT+1
// are landed for ALL waves (VMCNT(3) drains KT+1; 3 loads per tile).
// Stages issued 2 tiles ahead. 8 waves (2M x 4N), per-wave 64x64.
// 16B-chunk swizzle phys = c ^ ((row>>1)&3) on BOTH stage-source and ds_read.

#define BAR() do { asm volatile("" ::: "memory");          \
                   __builtin_amdgcn_s_barrier();           \
                   asm volatile("" ::: "memory"); } while (0)

#define VMCNT(N) asm volatile("s_waitcnt vmcnt(%0)" :: "n"(N) : "memory")

// TILE: BUF = KT % 3 (compile-time). S: stage tile KT+2 into buf (BUF+2)%3.
// WAR safe: buf (BUF+2)%3 == buf of KT-1; its reads completed (lgkm-consumed
// by MFMA) before the barrier that ended tile KT-1.
#define TILE(KT, BUF, S, VM) do {                                               \
    if (S) {                                                                    \
        load_lds16(gA0 + (size_t)((KT) + 2) * 64,                               \
                   lds + (((BUF) + 2) % 3) * 24576 + sdst);                     \
        load_lds16(gB0 + (size_t)((KT) + 2) * 64,                               \
                   lds + (((BUF) + 2) % 3) * 24576 + 8192 + sdst);              \
        load_lds16(gB0 + (size_t)128 * K_DIM + (size_t)((KT) + 2) * 64,         \
                   lds + (((BUF) + 2) % 3) * 24576 + 16384 + sdst);             \
    }                                                                           \
    _Pragma("unroll") for (int mm = 0; mm < 4; ++mm)                            \
        af[mm] = *(const v4i*)(lds + (BUF) * 24576 + aoff[mm]);                 \
    _Pragma("unroll") for (int nn = 0; nn < 4; ++nn)                            \
        bf[nn] = *(const v4i*)(lds + (BUF) * 24576 + boff[nn]);                 \
    __builtin_amdgcn_s_setprio(1);                                              \
    _Pragma("unroll") for (int mm = 0; mm < 4; ++mm)                            \
    _Pragma("unroll") for (int nn = 0; nn < 4; ++nn)                            \
        acc[mm][nn] = __builtin_amdgcn_mfma_i32_16x16x64_i8(                    \
            af[mm], bf[nn], acc[mm][nn], 0, 0, 0);                              \
    __builtin_amdgcn_s_setprio(0);                                              \
    VMCNT(VM);                                                                  \
    BAR();                                                                      \
} while (0)

__global__ __launch_bounds__(512, 4) void gemm_i8_kernel(
        const int8_t* __restrict__ qa, const int8_t* __restrict__ qbT,
        const float* __restrict__ sL, const float* __restrict__ sR,
        float* __restrict__ out) {
    __shared__ __align__(16) int8_t lds[73728];   // 3 bufs x (A 8KB + B 16KB)

    const int t = threadIdx.x;
    const int wave = t >> 6;
    const int lane = t & 63;

    // 2D XCD partition (R6/R7-validated): 1024 blocks, 8 XCDs (4x2 grid of
    // chunks); each XCD owns 16mt x 8nt. Bijective.
    const int bid = blockIdx.x;
    const int xcd = bid & 7;
    const int idx = bid >> 3;                     // 0..127
    const int mt = (xcd >> 1) * 16 + (idx & 15);  // 0..63 (128-row tiles)
    const int nt = (xcd & 1) * 8 + (idx >> 4);    // 0..15 (256-col tiles)
    const int brow = mt * 128;
    const int bcol = nt * 256;

    const int wm = (wave >> 2) * 64;     // 2 M-groups of 64 rows
    const int wn = (wave & 3) * 64;      // 4 N-groups of 64 cols

    // fragment read byte-offsets (relative to buf base; swizzled; 64B rows)
    // A region [0, 8KB): row 0..127; B region [8KB, 24KB): row 0..255.
    int aoff[4], boff[4];
#pragma unroll
    for (int m = 0; m < 4; ++m) {
        int row = wm + m * 16 + (lane & 15);
        aoff[m] = row * 64 + (((lane >> 4) ^ ((row >> 1) & 3)) * 16);
    }
#pragma unroll
    for (int n = 0; n < 4; ++n) {
        int row = wn + n * 16 + (lane & 15);
        boff[n] = 8192 + row * 64 + (((lane >> 4) ^ ((row >> 1) & 3)) * 16);
    }

    v4i acc[4][4];
#pragma unroll
    for (int m = 0; m < 4; ++m)
#pragma unroll
        for (int n = 0; n < 4; ++n) acc[m][n] = (v4i){0, 0, 0, 0};

    // staging: thread t covers bytes [t*16, t*16+16) of an 8KB region
    // (128 rows x 64B). Source chunk pre-swizzled so linear LDS holds the
    // swizzled layout. B's second 128 rows: row bit 7 doesn't affect
    // ((row>>1)&3), so the same lcA applies.
    const int srow = t >> 2;                                  // 0..127
    const int lcA = (t & 3) ^ ((srow >> 1) & 3);
    const int8_t* gA0 = qa  + (size_t)(brow + srow) * K_DIM + lcA * 16;
    const int8_t* gB0 = qbT + (size_t)(bcol + srow) * K_DIM + lcA * 16;
    const int sdst = t * 16;

    v4i af[4], bf[4];

    // prologue: stage T0 -> buf0, T1 -> buf1; drain T0; publish.
    load_lds16(gA0,                        lds + sdst);
    load_lds16(gB0,                        lds + 8192 + sdst);
    load_lds16(gB0 + (size_t)128 * K_DIM,  lds + 16384 + sdst);
    load_lds16(gA0 + 64,                       lds + 24576 + sdst);
    load_lds16(gB0 + 64,                       lds + 24576 + 8192 + sdst);
    load_lds16(gB0 + (size_t)128 * K_DIM + 64, lds + 24576 + 16384 + sdst);
    VMCNT(3);
    BAR();

    for (int kt = 0; kt < 60; kt += 3) {
        TILE(kt + 0, 0, 1, 3);
        TILE(kt + 1, 1, 1, 3);
        TILE(kt + 2, 2, 1, 3);
    }
    TILE(60, 0, 1, 3);   // stages T62; drains T61
    TILE(61, 1, 1, 3);   // stages T63; drains T62
    TILE(62, 2, 0, 0);   // drains T63
    TILE(63, 0, 0, 0);

    // Epilogue (validated): 16x16 C/D: col = lane&15, row = (lane>>4)*4 + reg
    const int r4 = (lane >> 4) * 4;
    const int cc = lane & 15;
#pragma unroll
    for (int m = 0; m < 4; ++m) {
        const int grow0 = brow + wm + m * 16 + r4;
        const float s0 = sL[grow0 + 0];
        const float s1 = sL[grow0 + 1];
        const float s2 = sL[grow0 + 2];
        const float s3 = sL[grow0 + 3];
#pragma unroll
        for (int n = 0; n < 4; ++n) {
            const int gcol = bcol + wn + n * 16 + cc;
            const float sc = sR[gcol];
            float* o = out + (size_t)grow0 * N_DIM + gcol;
            o[0 * N_DIM] = (float)acc[m][n][0] * s0 * sc;
            o[1 * N_DIM] = (float)acc[m][n][1] * s1 * sc;
            o[2 * N_DIM] = (float)acc[m][n][2] * s2 * sc;
            o[3 * N_DIM] = (float)acc[m][n][3] * s3 * sc;
        }
    }
}

// ---------------- launch ----------------
extern "C" void kernel_launch(void* const* d_in, const int* in_sizes, int n_in,
                              void* d_out, int out_size, void* d_ws, size_t ws_size,
                              hipStream_t stream) {
    const float* lhs = (const float*)d_in[0];
    const float* rhs = (const float*)d_in[1];
    float* out = (float*)d_out;

    uint8_t* ws = (uint8_t*)d_ws;
    int8_t* ql    = (int8_t*)ws;                               // 33,554,432 B
    int8_t* qbT   = (int8_t*)(ws + 33554432);                  // 16,777,216 B
    float* sL     = (float*)(ws + 50331648);                   // 32,768 B
    float* sR     = (float*)(ws + 50331648 + 32768);           // 16,384 B
    unsigned* bits = (unsigned*)(ws + 50331648 + 32768 + 16384); // 16,384 B

    hipMemsetAsync(bits, 0, N_DIM * sizeof(unsigned), stream);

    prep1_kernel<<<M_DIM + 1024, 256, 0, stream>>>(lhs, rhs, sL, bits, ql);
    quant_rhs_t_kernel<<<dim3(N_DIM / 64, K_DIM / 64), 256, 0, stream>>>(
        rhs, bits, sR, qbT);
    gemm_i8_kernel<<<dim3((M_DIM / 128) * (N_DIM / 256)), 512, 0, stream>>>(
        ql, qbT, sL, sR, out);
}